// Round 4
// baseline (514.252 us; speedup 1.0000x reference)
//
#include <hip/hip_runtime.h>
#include <hip/hip_bf16.h>

typedef __bf16 bf16x8 __attribute__((ext_vector_type(8)));
typedef __bf16 bf16x4 __attribute__((ext_vector_type(4)));
typedef float  f32x4  __attribute__((ext_vector_type(4)));

#define DEVI __device__ __forceinline__

DEVI float bf2f(__hip_bfloat16 x) { return __bfloat162float(x); }
DEVI __hip_bfloat16 f2bf(float x) { return __float2bfloat16(x); }

DEVI f32x4 mfma16(bf16x8 a, bf16x8 b, f32x4 c) {
    return __builtin_amdgcn_mfma_f32_16x16x32_bf16(a, b, c, 0, 0, 0);
}

DEVI bf16x8 ld8(const __hip_bfloat16* p) {
    return *reinterpret_cast<const bf16x8*>(p);
}

// convert 8 contiguous fp32 -> bf16x8 (two float4 vector loads)
DEVI bf16x8 cvt8(const float* p) {
    f32x4 u = *reinterpret_cast<const f32x4*>(p);
    f32x4 v = *reinterpret_cast<const f32x4*>(p + 4);
    bf16x8 r;
    r[0] = (__bf16)u[0]; r[1] = (__bf16)u[1]; r[2] = (__bf16)u[2]; r[3] = (__bf16)u[3];
    r[4] = (__bf16)v[0]; r[5] = (__bf16)v[1]; r[6] = (__bf16)v[2]; r[7] = (__bf16)v[3];
    return r;
}

// pack two f32 -> one u32 of 2 bf16 (lo = a, hi = b), RNE
DEVI unsigned cvtpk(float a, float b) {
    unsigned r;
    asm("v_cvt_pk_bf16_f32 %0, %1, %2" : "=v"(r) : "v"(a), "v"(b));
    return r;
}

DEVI bf16x8 u4bf(unsigned x0, unsigned x1, unsigned x2, unsigned x3) {
    union { unsigned u[4]; bf16x8 b; } cv;
    cv.u[0] = x0; cv.u[1] = x1; cv.u[2] = x2; cv.u[3] = x3;
    return cv.b;
}

// zero-extend a 4-elem (k=16-style) fragment to the 16x16x32 register shape.
// Both operands use the same slot placement; extra slots zero -> exact k=16 MFMA.
DEVI bf16x8 pad4(bf16x4 v) {
    bf16x8 r = {};
    r[0] = v[0]; r[1] = v[1]; r[2] = v[2]; r[3] = v[3];
    return r;
}

// ---------------------------------------------------------------------------
// Sizes: B=64, N=256, D=128, H=8, DK=16, FF=512.  All external I/O fp32.
// LayerNorm stats flow: attn emits (S,SQ) atomics per batch -> ffln applies
// LN1 inline; ffln emits stats2 -> ln_apply applies LN2. No standalone LN pass.
// ---------------------------------------------------------------------------

// K0: repack fp32 weights into MFMA-B-friendly bf16 layouts; zero stats buffers
__global__ __launch_bounds__(256) void repack_kernel(
    const float* __restrict__ Wq, const float* __restrict__ Wk,
    const float* __restrict__ Wv, const float* __restrict__ W_out,
    const float* __restrict__ ff_w1, const float* __restrict__ ff_w2,
    __hip_bfloat16* __restrict__ Wqkvt, __hip_bfloat16* __restrict__ Wot,
    __hip_bfloat16* __restrict__ w1t, __hip_bfloat16* __restrict__ w2t,
    float* __restrict__ stats)
{
    int t = blockIdx.x * 256 + threadIdx.x;
    if (t < 256) stats[t] = 0.f;          // stats1[128] | stats2[128]
    if (t < 49152) {                       // Wqkvt[c][d], c = qkv*128 + h*16 + k
        int c = t >> 7, d = t & 127;
        int qkv = c >> 7, h = (c >> 4) & 7, k = c & 15;
        const float* W = (qkv == 0) ? Wq : (qkv == 1) ? Wk : Wv;
        Wqkvt[t] = f2bf(W[(h * 128 + d) * 16 + k]);
    } else if (t < 65536) {                // Wot[d][h*16+v] = W_out[h][v][d]
        int idx = t - 49152;
        int d = idx >> 7, hv = idx & 127, h = hv >> 4, v = hv & 15;
        Wot[idx] = f2bf(W_out[(h * 16 + v) * 128 + d]);
    } else if (t < 131072) {               // w1t[f][d] = ff_w1[d][f]
        int idx = t - 65536;
        int f = idx >> 7, d = idx & 127;
        w1t[idx] = f2bf(ff_w1[d * 512 + f]);
    } else {                               // w2t[d2][f] = ff_w2[f][d2]
        int idx = t - 131072;
        int d2 = idx >> 9, f = idx & 511;
        w2t[idx] = f2bf(ff_w2[f * 128 + d2]);
    }
}

// K1 v2: QKV projection with LDS staging.
//   - h_em tile (32 rows x 128) loaded coalesced (float4), bf16 in LDS.
//   - Q/K stored direct (32-B segments); V transposed via LDS -> 64-B segments.
__global__ __launch_bounds__(512) void qkv_kernel(
    const float* __restrict__ hem, const __hip_bfloat16* __restrict__ Wqkvt,
    __hip_bfloat16* __restrict__ Qb, __hip_bfloat16* __restrict__ Kb,
    __hip_bfloat16* __restrict__ Vtb)
{
    __shared__ alignas(16) __hip_bfloat16 hemt[32][136];
    __shared__ alignas(16) __hip_bfloat16 vt[128][34];
    const int tid = threadIdx.x;
    const int w = tid >> 6, lane = tid & 63;
    const int quad = lane >> 4, col = lane & 15;
    const int row0 = blockIdx.x * 32;

    {   // stage h_em tile: thread t -> row tid>>4, cols (tid&15)*8..+8
        int r = tid >> 4, c8 = (tid & 15) * 8;
        *reinterpret_cast<bf16x8*>(&hemt[r][c8]) =
            cvt8(hem + (size_t)(row0 + r) * 128 + c8);
    }
    __syncthreads();

    f32x4 acc[2][3] = {};
#pragma unroll
    for (int ks = 0; ks < 4; ++ks) {
        bf16x8 a[2], bb[3];
#pragma unroll
        for (int mt = 0; mt < 2; ++mt)
            a[mt] = ld8(&hemt[mt * 16 + col][ks * 32 + quad * 8]);
#pragma unroll
        for (int nt = 0; nt < 3; ++nt) {
            int c = (w * 3 + nt) * 16 + col;
            bb[nt] = ld8(Wqkvt + (size_t)c * 128 + ks * 32 + quad * 8);
        }
#pragma unroll
        for (int mt = 0; mt < 2; ++mt)
#pragma unroll
            for (int nt = 0; nt < 3; ++nt)
                acc[mt][nt] = mfma16(a[mt], bb[nt], acc[mt][nt]);
    }
    const int bb_ = row0 >> 8, nbase = row0 & 255;
#pragma unroll
    for (int mt = 0; mt < 2; ++mt)
#pragma unroll
        for (int nt = 0; nt < 3; ++nt)
#pragma unroll
            for (int rg = 0; rg < 4; ++rg) {
                int rl = mt * 16 + quad * 4 + rg;
                int c = (w * 3 + nt) * 16 + col;
                __hip_bfloat16 v = f2bf(acc[mt][nt][rg]);
                if (c < 128) {
                    int h = c >> 4, k = c & 15;
                    Qb[(((size_t)bb_ * 8 + h) * 256 + nbase + rl) * 16 + k] = v;
                } else if (c < 256) {
                    int h = (c >> 4) & 7, k = c & 15;
                    Kb[(((size_t)bb_ * 8 + h) * 256 + nbase + rl) * 16 + k] = v;
                } else {
                    vt[c - 256][rl] = v;   // LDS transpose for coalesced store
                }
            }
    __syncthreads();
    {   // V store: thread t -> kk = t>>2, n-chunk (t&3)*8 (16 B, 64-B/row segs)
        int kk = tid >> 2, nl = (tid & 3) * 8;
        bf16x8 vv = *reinterpret_cast<const bf16x8*>(&vt[kk][nl]);
        int h = kk >> 4, k = kk & 15;
        *reinterpret_cast<bf16x8*>(
            &Vtb[(((size_t)bb_ * 8 + h) * 16 + k) * 256 + nbase + nl]) = vv;
    }
}

// K2 v6: fused attention (= v5) + per-block LN1 stats atomics.
__global__ __launch_bounds__(512, 4) void attn_kernel_v6(
    const __hip_bfloat16* __restrict__ Qb, const __hip_bfloat16* __restrict__ Kb,
    const __hip_bfloat16* __restrict__ Vtb, const float* __restrict__ route,
    const float* __restrict__ sa_w1, const float* __restrict__ sa_b1,
    const float* __restrict__ sa_w2, const float* __restrict__ sa_b2,
    const float* __restrict__ h_em, const __hip_bfloat16* __restrict__ Wot,
    float* __restrict__ y, float* __restrict__ out, float* __restrict__ stats1)
{
    __shared__ alignas(16) __hip_bfloat16 srb[2 * 2048 * 8 + 8];  // sb | pad | rb
    __shared__ alignas(16) __hip_bfloat16 headsb[8][144];
    __shared__ alignas(16) __hip_bfloat16 saw1t16[16][16];
    __shared__ alignas(16) __hip_bfloat16 saw2t16[16][16];
    __shared__ float b1s[16];
    __hip_bfloat16* sb = srb;                // [2048][8] scores ch0-7; later soft slabs
    __hip_bfloat16* rb = srb + 16384 + 8;    // [2048][8] route  ch8-15

    const int tid = threadIdx.x;
    const int w = tid >> 6, lane = tid & 63, quad = lane >> 4, col = lane & 15;
    const int quad4 = quad * 4;
    const int b = blockIdx.x >> 5, tile = blockIdx.x & 31, n0 = tile * 8;
    const f32x4 zero = {0.f, 0.f, 0.f, 0.f};

    {   // P0: stage score_aggr weights in k=16 layout
        if (tid < 256) {
            int o = tid >> 4, i = tid & 15;
            saw1t16[o][i] = f2bf(sa_w1[i * 16 + o]);
            saw2t16[o][i] = (o < 8) ? f2bf(sa_w2[i * 8 + o]) : f2bf(0.f);
        }
        if (tid < 16) b1s[tid] = sa_b1[tid];
    }

    {   // P1: route prefetch (scalar) + QK^T scores + route copy/stage
        const int h = w;
        const size_t rbase = (((size_t)h * 64 + b) * 256 + n0) * 256;
        const float* rsrc = route + rbase;
        float rv[32];
#pragma unroll
        for (int r = 0; r < 8; ++r)
#pragma unroll
            for (int j = 0; j < 4; ++j)
                rv[r * 4 + j] = rsrc[r * 256 + j * 64 + lane];

        const __hip_bfloat16* Qh = Qb + ((size_t)(b * 8 + h)) * 256 * 16;
        const __hip_bfloat16* Kh = Kb + ((size_t)(b * 8 + h)) * 256 * 16;
        bf16x8 aq = ld8(Qh + (size_t)(n0 + (col & 7)) * 16 + (quad & 1) * 8);
#pragma unroll
        for (int nt = 0; nt < 16; ++nt) {
            bf16x8 bk = {};
            if (quad < 2) bk = ld8(Kh + (size_t)(nt * 16 + col) * 16 + quad * 8);
            f32x4 c = mfma16(aq, bk, zero);
            if (quad < 2) {
#pragma unroll
                for (int rg = 0; rg < 4; ++rg)
                    sb[((quad * 4 + rg) * 256 + nt * 16 + col) * 8 + h] = f2bf(c[rg]);
            }
        }
        float* rdst = out + 2097152 + rbase;
#pragma unroll
        for (int r = 0; r < 8; ++r)
#pragma unroll
            for (int j = 0; j < 4; ++j) {
                int nm = r * 256 + j * 64 + lane;
                float v = rv[r * 4 + j];
                rdst[nm] = v;                 // fp32 passthrough copy (exact)
                rb[nm * 8 + h] = f2bf(v);     // stage transposed
            }
    }
    __syncthreads();

    float lg[4][16];   // logits: [head rg][t8]
    {   // P2: score_aggr via exact k=16 MFMAs; hidden+logits in registers
        bf16x8 a1 = pad4(*(const bf16x4*)&saw1t16[col][quad4]);
        bf16x8 a2 = pad4(*(const bf16x4*)&saw2t16[col][quad4]);
        f32x4 bv1 = *(const f32x4*)&b1s[quad4];
        const char* aptr = (const char*)((quad & 2) ? rb : sb) + (quad & 1) * 8;
        const int rowbase = (w * 256 + col) * 16;

        bf16x4 b4 = *(const bf16x4*)(aptr + rowbase);
#pragma unroll
        for (int t8 = 0; t8 < 16; ++t8) {
            bf16x8 b1 = pad4(b4);
            if (t8 < 15) b4 = *(const bf16x4*)(aptr + rowbase + (t8 + 1) * 256);
            f32x4 c1 = mfma16(a1, b1, zero);
            unsigned q0 = cvtpk(fmaxf(c1[0] + bv1[0], 0.f), fmaxf(c1[1] + bv1[1], 0.f));
            unsigned q1 = cvtpk(fmaxf(c1[2] + bv1[2], 0.f), fmaxf(c1[3] + bv1[3], 0.f));
            f32x4 c2 = mfma16(a2, u4bf(q0, q1, 0, 0), zero);
#pragma unroll
            for (int rg = 0; rg < 4; ++rg) lg[rg][t8] = c2[rg];
        }
    }

    float inv[4];
    {   // P3: register softmax over m=256 per (head, n=w)
#pragma unroll
        for (int rg = 0; rg < 4; ++rg) {
            float mx = lg[rg][0];
#pragma unroll
            for (int t = 1; t < 16; ++t) mx = fmaxf(mx, lg[rg][t]);
#pragma unroll
            for (int off = 1; off < 16; off <<= 1) mx = fmaxf(mx, __shfl_xor(mx, off, 64));
            float s = 0.f;
#pragma unroll
            for (int t = 0; t < 16; ++t) {
                float e = __expf(lg[rg][t] - mx);
                lg[rg][t] = e; s += e;
            }
#pragma unroll
            for (int off = 1; off < 16; off <<= 1) s += __shfl_xor(s, off, 64);
            inv[rg] = 1.f / s;
        }
    }
    __syncthreads();   // all P2 reads done before soft overwrites sb

    {   // P3b: write soft bf16 into per-head slabs (XOR-swizzled), quads 0,1
        if (quad < 2) {
            const int swz = w << 4;
#pragma unroll
            for (int rg = 0; rg < 4; ++rg) {
                char* slab = (char*)srb + (quad4 + rg) * 4096 + w * 512;
                float iv = inv[rg];
#pragma unroll
                for (int t = 0; t < 16; ++t)
                    *(__hip_bfloat16*)(slab + (((t * 16 + col) * 2) ^ swz)) = f2bf(lg[rg][t] * iv);
            }
        }
    }
    __syncthreads();

    {   // P4: PV (wave w <-> head h=w)
        const int h = w;
        f32x4 acc = zero;
        const __hip_bfloat16* Vh = Vtb + ((size_t)(b * 8 + h)) * 16 * 256;
        const char* softh = (const char*)srb + h * 4096 + (col & 7) * 512;
        const int sx = (col & 7) << 4;
#pragma unroll
        for (int ks = 0; ks < 8; ++ks) {
            bf16x8 a = *(const bf16x8*)(softh + ((ks * 64 + quad * 16) ^ sx));
            bf16x8 bv = ld8(Vh + (size_t)col * 256 + ks * 32 + quad * 8);
            acc = mfma16(a, bv, acc);
        }
        if (quad < 2) {
#pragma unroll
            for (int rg = 0; rg < 4; ++rg)
                headsb[quad * 4 + rg][h * 16 + col] = f2bf(acc[rg]);
        }
    }
    __syncthreads();

    {   // P5: out-proj + residual -> y (fp32) + LN1 stats atomics
        f32x4 acc = zero;
#pragma unroll
        for (int ks = 0; ks < 4; ++ks) {
            bf16x8 a = *(const bf16x8*)&headsb[col & 7][ks * 32 + quad * 8];
            bf16x8 bo = ld8(Wot + (size_t)(w * 16 + col) * 128 + ks * 32 + quad * 8);
            acc = mfma16(a, bo, acc);
        }
        float s = 0.f, sq = 0.f;
        if (quad < 2) {
#pragma unroll
            for (int rg = 0; rg < 4; ++rg) {
                int n = n0 + quad * 4 + rg, d = w * 16 + col;
                size_t idx = ((size_t)b * 256 + n) * 128 + d;
                float yv_ = acc[rg] + h_em[idx];
                y[idx] = yv_;
                s += yv_; sq += yv_ * yv_;
            }
        }
#pragma unroll
        for (int off = 32; off; off >>= 1) {
            s += __shfl_xor(s, off, 64);
            sq += __shfl_xor(sq, off, 64);
        }
        if (lane == 0) {
            atomicAdd(&stats1[b * 2], s);
            atomicAdd(&stats1[b * 2 + 1], sq);
        }
    }
}

// K3: fused LN1-apply + FF + residual + LN2-stats. 32-row tiles, in-place y->y2.
__global__ __launch_bounds__(512) void ffln_kernel(
    float* __restrict__ y, const float* __restrict__ stats1,
    const __hip_bfloat16* __restrict__ w1t, const __hip_bfloat16* __restrict__ w2t,
    float* __restrict__ stats2)
{
    __shared__ alignas(16) __hip_bfloat16 xt[32][136];
    __shared__ alignas(16) __hip_bfloat16 hid[32][520];
    const int tid = threadIdx.x;
    const int w = tid >> 6, lane = tid & 63;
    const int quad = lane >> 4, col = lane & 15;
    const int r0 = blockIdx.x * 32, b = r0 >> 8;

    float s1 = stats1[b * 2], q1 = stats1[b * 2 + 1];
    float mean = s1 * (1.f / 32768.f);
    float var = fmaxf((q1 - s1 * mean) * (1.f / 32767.f), 0.f);
    float rstd = rsqrtf(var + 1e-5f);

    {   // LN1-apply head: load y tile coalesced, normalize, stage bf16
        int r = tid >> 4, c8 = (tid & 15) * 8;
        const float* p = y + (size_t)(r0 + r) * 128 + c8;
        f32x4 u = *reinterpret_cast<const f32x4*>(p);
        f32x4 v = *reinterpret_cast<const f32x4*>(p + 4);
        bf16x8 xv;
#pragma unroll
        for (int j = 0; j < 4; ++j) xv[j] = (__bf16)((u[j] - mean) * rstd);
#pragma unroll
        for (int j = 0; j < 4; ++j) xv[4 + j] = (__bf16)((v[j] - mean) * rstd);
        *reinterpret_cast<bf16x8*>(&xt[r][c8]) = xv;
    }
    __syncthreads();

    f32x4 acc[2][4] = {};
#pragma unroll
    for (int ks = 0; ks < 4; ++ks) {
        bf16x8 a[2], bb[4];
#pragma unroll
        for (int mt = 0; mt < 2; ++mt)
            a[mt] = ld8(&xt[mt * 16 + col][ks * 32 + quad * 8]);
#pragma unroll
        for (int nt = 0; nt < 4; ++nt) {
            int f = (w * 4 + nt) * 16 + col;
            bb[nt] = ld8(w1t + (size_t)f * 128 + ks * 32 + quad * 8);
        }
#pragma unroll
        for (int mt = 0; mt < 2; ++mt)
#pragma unroll
            for (int nt = 0; nt < 4; ++nt)
                acc[mt][nt] = mfma16(a[mt], bb[nt], acc[mt][nt]);
    }
#pragma unroll
    for (int mt = 0; mt < 2; ++mt)
#pragma unroll
        for (int nt = 0; nt < 4; ++nt)
#pragma unroll
            for (int rg = 0; rg < 4; ++rg) {
                int row = mt * 16 + quad * 4 + rg;
                int f = (w * 4 + nt) * 16 + col;
                hid[row][f] = f2bf(fmaxf(acc[mt][nt][rg], 0.f));
            }
    __syncthreads();

    f32x4 acc2[2] = {};
#pragma unroll
    for (int ks = 0; ks < 16; ++ks) {
        bf16x8 bb = ld8(w2t + (size_t)(w * 16 + col) * 512 + ks * 32 + quad * 8);
#pragma unroll
        for (int mt = 0; mt < 2; ++mt) {
            bf16x8 a = *(const bf16x8*)&hid[mt * 16 + col][ks * 32 + quad * 8];
            acc2[mt] = mfma16(a, bb, acc2[mt]);
        }
    }
    float s = 0.f, sq = 0.f;
#pragma unroll
    for (int mt = 0; mt < 2; ++mt)
#pragma unroll
        for (int rg = 0; rg < 4; ++rg) {
            int row = r0 + mt * 16 + quad * 4 + rg;
            int d = w * 16 + col;
            size_t idx = (size_t)row * 128 + d;
            float xn = (y[idx] - mean) * rstd;   // fp32 residual (L2-hot re-read)
            float o = acc2[mt][rg] + xn;
            y[idx] = o;                          // in-place: own idx only
            s += o; sq += o * o;
        }
#pragma unroll
    for (int off = 32; off; off >>= 1) {
        s += __shfl_xor(s, off, 64);
        sq += __shfl_xor(sq, off, 64);
    }
    if (lane == 0) {
        atomicAdd(&stats2[b * 2], s);
        atomicAdd(&stats2[b * 2 + 1], sq);
    }
}

// K4: LN2 apply, wide grid. 2048 blocks x 256 thr x float4 = 2,097,152 elems.
__global__ __launch_bounds__(256) void ln_apply_kernel(
    const float* __restrict__ y2, const float* __restrict__ stats2,
    float* __restrict__ out1)
{
    int i = (blockIdx.x * 256 + threadIdx.x) * 4;
    int b = i >> 15;
    float s = stats2[b * 2], q = stats2[b * 2 + 1];
    float mean = s * (1.f / 32768.f);
    float var = fmaxf((q - s * mean) * (1.f / 32767.f), 0.f);
    float rstd = rsqrtf(var + 1e-5f);
    f32x4 v = *reinterpret_cast<const f32x4*>(&y2[i]);
#pragma unroll
    for (int j = 0; j < 4; ++j) v[j] = (v[j] - mean) * rstd;
    *reinterpret_cast<f32x4*>(&out1[i]) = v;
}

extern "C" void kernel_launch(void* const* d_in, const int* in_sizes, int n_in,
                              void* d_out, int out_size, void* d_ws, size_t ws_size,
                              hipStream_t stream)
{
    const float* h_em  = (const float*)d_in[0];
    const float* route = (const float*)d_in[1];
    const float* Wq    = (const float*)d_in[2];
    const float* Wk    = (const float*)d_in[3];
    const float* Wv    = (const float*)d_in[4];
    const float* W_out = (const float*)d_in[5];
    const float* sa_w1 = (const float*)d_in[6];
    const float* sa_b1 = (const float*)d_in[7];
    const float* sa_w2 = (const float*)d_in[8];
    const float* sa_b2 = (const float*)d_in[9];
    const float* ff_w1 = (const float*)d_in[10];
    const float* ff_w2 = (const float*)d_in[11];

    char* ws = (char*)d_ws;
    __hip_bfloat16* Qb    = (__hip_bfloat16*)(ws);
    __hip_bfloat16* Kb    = (__hip_bfloat16*)(ws + 4194304);
    __hip_bfloat16* Vtb   = (__hip_bfloat16*)(ws + 8388608);
    __hip_bfloat16* Wqkvt = (__hip_bfloat16*)(ws + 12582912);
    __hip_bfloat16* Wot   = (__hip_bfloat16*)(ws + 12681216);
    __hip_bfloat16* w1t   = (__hip_bfloat16*)(ws + 12713984);
    __hip_bfloat16* w2t   = (__hip_bfloat16*)(ws + 12845056);
    float*          yv    = (float*)(ws + 12976128);
    float*          stats = (float*)(ws + 21364736);  // stats1[128] | stats2[128]
    float*          stats1 = stats;
    float*          stats2 = stats + 128;

    hipLaunchKernelGGL(repack_kernel, dim3(768), dim3(256), 0, stream,
                       Wq, Wk, Wv, W_out, ff_w1, ff_w2, Wqkvt, Wot, w1t, w2t, stats);
    hipLaunchKernelGGL(qkv_kernel, dim3(512), dim3(512), 0, stream,
                       h_em, Wqkvt, Qb, Kb, Vtb);
    hipLaunchKernelGGL(attn_kernel_v6, dim3(2048), dim3(512), 0, stream,
                       Qb, Kb, Vtb, route, sa_w1, sa_b1, sa_w2, sa_b2, h_em, Wot,
                       yv, (float*)d_out, stats1);
    hipLaunchKernelGGL(ffln_kernel, dim3(512), dim3(512), 0, stream,
                       yv, stats1, w1t, w2t, stats2);
    hipLaunchKernelGGL(ln_apply_kernel, dim3(2048), dim3(256), 0, stream,
                       yv, stats2, (float*)d_out);
}

// Round 5
// 346.947 us; speedup vs baseline: 1.4822x; 1.4822x over previous
//
#include <hip/hip_runtime.h>
#include <hip/hip_bf16.h>

typedef __bf16 bf16x8 __attribute__((ext_vector_type(8)));
typedef __bf16 bf16x4 __attribute__((ext_vector_type(4)));
typedef float  f32x4  __attribute__((ext_vector_type(4)));

#define DEVI __device__ __forceinline__

DEVI float bf2f(__hip_bfloat16 x) { return __bfloat162float(x); }
DEVI __hip_bfloat16 f2bf(float x) { return __float2bfloat16(x); }

DEVI f32x4 mfma16(bf16x8 a, bf16x8 b, f32x4 c) {
    return __builtin_amdgcn_mfma_f32_16x16x32_bf16(a, b, c, 0, 0, 0);
}

DEVI bf16x8 ld8(const __hip_bfloat16* p) {
    return *reinterpret_cast<const bf16x8*>(p);
}

// convert 8 contiguous fp32 -> bf16x8 (two float4 vector loads)
DEVI bf16x8 cvt8(const float* p) {
    f32x4 u = *reinterpret_cast<const f32x4*>(p);
    f32x4 v = *reinterpret_cast<const f32x4*>(p + 4);
    bf16x8 r;
    r[0] = (__bf16)u[0]; r[1] = (__bf16)u[1]; r[2] = (__bf16)u[2]; r[3] = (__bf16)u[3];
    r[4] = (__bf16)v[0]; r[5] = (__bf16)v[1]; r[6] = (__bf16)v[2]; r[7] = (__bf16)v[3];
    return r;
}

// pack two f32 -> one u32 of 2 bf16 (lo = a, hi = b), RNE
DEVI unsigned cvtpk(float a, float b) {
    unsigned r;
    asm("v_cvt_pk_bf16_f32 %0, %1, %2" : "=v"(r) : "v"(a), "v"(b));
    return r;
}

DEVI bf16x8 u4bf(unsigned x0, unsigned x1, unsigned x2, unsigned x3) {
    union { unsigned u[4]; bf16x8 b; } cv;
    cv.u[0] = x0; cv.u[1] = x1; cv.u[2] = x2; cv.u[3] = x3;
    return cv.b;
}

// zero-extend a 4-elem (k=16-style) fragment to the 16x16x32 register shape.
// Both operands use the same slot placement; extra slots zero -> exact k=16 MFMA.
DEVI bf16x8 pad4(bf16x4 v) {
    bf16x8 r = {};
    r[0] = v[0]; r[1] = v[1]; r[2] = v[2]; r[3] = v[3];
    return r;
}

// ---------------------------------------------------------------------------
// Sizes: B=64, N=256, D=128, H=8, DK=16, FF=512.  All external I/O fp32.
// LayerNorm stats flow: attn emits ONE (S,SQ) atomic pair per block into a
// per-batch 128-B-padded slot (b*32) -> ffln applies LN1 inline; ffln emits
// stats2 the same way -> ln_apply applies LN2. No standalone LN pass.
// Atomic budget: attn 2048 pairs (32/addr), ffln 512 pairs (8/addr).
// ---------------------------------------------------------------------------

// K0: repack fp32 weights into MFMA-B-friendly bf16 layouts; zero stats buffers
__global__ __launch_bounds__(256) void repack_kernel(
    const float* __restrict__ Wq, const float* __restrict__ Wk,
    const float* __restrict__ Wv, const float* __restrict__ W_out,
    const float* __restrict__ ff_w1, const float* __restrict__ ff_w2,
    __hip_bfloat16* __restrict__ Wqkvt, __hip_bfloat16* __restrict__ Wot,
    __hip_bfloat16* __restrict__ w1t, __hip_bfloat16* __restrict__ w2t,
    float* __restrict__ stats)
{
    int t = blockIdx.x * 256 + threadIdx.x;
    if (t < 4096) stats[t] = 0.f;          // stats1[2048] | stats2[2048]
    if (t < 49152) {                       // Wqkvt[c][d], c = qkv*128 + h*16 + k
        int c = t >> 7, d = t & 127;
        int qkv = c >> 7, h = (c >> 4) & 7, k = c & 15;
        const float* W = (qkv == 0) ? Wq : (qkv == 1) ? Wk : Wv;
        Wqkvt[t] = f2bf(W[(h * 128 + d) * 16 + k]);
    } else if (t < 65536) {                // Wot[d][h*16+v] = W_out[h][v][d]
        int idx = t - 49152;
        int d = idx >> 7, hv = idx & 127, h = hv >> 4, v = hv & 15;
        Wot[idx] = f2bf(W_out[(h * 16 + v) * 128 + d]);
    } else if (t < 131072) {               // w1t[f][d] = ff_w1[d][f]
        int idx = t - 65536;
        int f = idx >> 7, d = idx & 127;
        w1t[idx] = f2bf(ff_w1[d * 512 + f]);
    } else {                               // w2t[d2][f] = ff_w2[f][d2]
        int idx = t - 131072;
        int d2 = idx >> 9, f = idx & 511;
        w2t[idx] = f2bf(ff_w2[f * 128 + d2]);
    }
}

// K1 v2: QKV projection with LDS staging.
//   - h_em tile (32 rows x 128) loaded coalesced (float4), bf16 in LDS.
//   - Q/K stored direct (32-B segments); V transposed via LDS -> 64-B segments.
__global__ __launch_bounds__(512) void qkv_kernel(
    const float* __restrict__ hem, const __hip_bfloat16* __restrict__ Wqkvt,
    __hip_bfloat16* __restrict__ Qb, __hip_bfloat16* __restrict__ Kb,
    __hip_bfloat16* __restrict__ Vtb)
{
    __shared__ alignas(16) __hip_bfloat16 hemt[32][136];
    __shared__ alignas(16) __hip_bfloat16 vt[128][34];
    const int tid = threadIdx.x;
    const int w = tid >> 6, lane = tid & 63;
    const int quad = lane >> 4, col = lane & 15;
    const int row0 = blockIdx.x * 32;

    {   // stage h_em tile: thread t -> row tid>>4, cols (tid&15)*8..+8
        int r = tid >> 4, c8 = (tid & 15) * 8;
        *reinterpret_cast<bf16x8*>(&hemt[r][c8]) =
            cvt8(hem + (size_t)(row0 + r) * 128 + c8);
    }
    __syncthreads();

    f32x4 acc[2][3] = {};
#pragma unroll
    for (int ks = 0; ks < 4; ++ks) {
        bf16x8 a[2], bb[3];
#pragma unroll
        for (int mt = 0; mt < 2; ++mt)
            a[mt] = ld8(&hemt[mt * 16 + col][ks * 32 + quad * 8]);
#pragma unroll
        for (int nt = 0; nt < 3; ++nt) {
            int c = (w * 3 + nt) * 16 + col;
            bb[nt] = ld8(Wqkvt + (size_t)c * 128 + ks * 32 + quad * 8);
        }
#pragma unroll
        for (int mt = 0; mt < 2; ++mt)
#pragma unroll
            for (int nt = 0; nt < 3; ++nt)
                acc[mt][nt] = mfma16(a[mt], bb[nt], acc[mt][nt]);
    }
    const int bb_ = row0 >> 8, nbase = row0 & 255;
#pragma unroll
    for (int mt = 0; mt < 2; ++mt)
#pragma unroll
        for (int nt = 0; nt < 3; ++nt)
#pragma unroll
            for (int rg = 0; rg < 4; ++rg) {
                int rl = mt * 16 + quad * 4 + rg;
                int c = (w * 3 + nt) * 16 + col;
                __hip_bfloat16 v = f2bf(acc[mt][nt][rg]);
                if (c < 128) {
                    int h = c >> 4, k = c & 15;
                    Qb[(((size_t)bb_ * 8 + h) * 256 + nbase + rl) * 16 + k] = v;
                } else if (c < 256) {
                    int h = (c >> 4) & 7, k = c & 15;
                    Kb[(((size_t)bb_ * 8 + h) * 256 + nbase + rl) * 16 + k] = v;
                } else {
                    vt[c - 256][rl] = v;   // LDS transpose for coalesced store
                }
            }
    __syncthreads();
    {   // V store: thread t -> kk = t>>2, n-chunk (t&3)*8 (16 B, 64-B/row segs)
        int kk = tid >> 2, nl = (tid & 3) * 8;
        bf16x8 vv = *reinterpret_cast<const bf16x8*>(&vt[kk][nl]);
        int h = kk >> 4, k = kk & 15;
        *reinterpret_cast<bf16x8*>(
            &Vtb[(((size_t)bb_ * 8 + h) * 16 + k) * 256 + nbase + nl]) = vv;
    }
}

// K2 v7: fused attention (= v5) + LN1 stats: block-level LDS reduction,
// single atomic pair per block into per-batch padded slot stats1[b*32].
__global__ __launch_bounds__(512, 4) void attn_kernel_v7(
    const __hip_bfloat16* __restrict__ Qb, const __hip_bfloat16* __restrict__ Kb,
    const __hip_bfloat16* __restrict__ Vtb, const float* __restrict__ route,
    const float* __restrict__ sa_w1, const float* __restrict__ sa_b1,
    const float* __restrict__ sa_w2, const float* __restrict__ sa_b2,
    const float* __restrict__ h_em, const __hip_bfloat16* __restrict__ Wot,
    float* __restrict__ y, float* __restrict__ out, float* __restrict__ stats1)
{
    __shared__ alignas(16) __hip_bfloat16 srb[2 * 2048 * 8 + 8];  // sb | pad | rb
    __shared__ alignas(16) __hip_bfloat16 headsb[8][144];
    __shared__ alignas(16) __hip_bfloat16 saw1t16[16][16];
    __shared__ alignas(16) __hip_bfloat16 saw2t16[16][16];
    __shared__ float b1s[16];
    __shared__ float psum[8], qsum[8];
    __hip_bfloat16* sb = srb;                // [2048][8] scores ch0-7; later soft slabs
    __hip_bfloat16* rb = srb + 16384 + 8;    // [2048][8] route  ch8-15

    const int tid = threadIdx.x;
    const int w = tid >> 6, lane = tid & 63, quad = lane >> 4, col = lane & 15;
    const int quad4 = quad * 4;
    const int b = blockIdx.x >> 5, tile = blockIdx.x & 31, n0 = tile * 8;
    const f32x4 zero = {0.f, 0.f, 0.f, 0.f};

    {   // P0: stage score_aggr weights in k=16 layout
        if (tid < 256) {
            int o = tid >> 4, i = tid & 15;
            saw1t16[o][i] = f2bf(sa_w1[i * 16 + o]);
            saw2t16[o][i] = (o < 8) ? f2bf(sa_w2[i * 8 + o]) : f2bf(0.f);
        }
        if (tid < 16) b1s[tid] = sa_b1[tid];
    }

    {   // P1: route prefetch (scalar) + QK^T scores + route copy/stage
        const int h = w;
        const size_t rbase = (((size_t)h * 64 + b) * 256 + n0) * 256;
        const float* rsrc = route + rbase;
        float rv[32];
#pragma unroll
        for (int r = 0; r < 8; ++r)
#pragma unroll
            for (int j = 0; j < 4; ++j)
                rv[r * 4 + j] = rsrc[r * 256 + j * 64 + lane];

        const __hip_bfloat16* Qh = Qb + ((size_t)(b * 8 + h)) * 256 * 16;
        const __hip_bfloat16* Kh = Kb + ((size_t)(b * 8 + h)) * 256 * 16;
        bf16x8 aq = ld8(Qh + (size_t)(n0 + (col & 7)) * 16 + (quad & 1) * 8);
#pragma unroll
        for (int nt = 0; nt < 16; ++nt) {
            bf16x8 bk = {};
            if (quad < 2) bk = ld8(Kh + (size_t)(nt * 16 + col) * 16 + quad * 8);
            f32x4 c = mfma16(aq, bk, zero);
            if (quad < 2) {
#pragma unroll
                for (int rg = 0; rg < 4; ++rg)
                    sb[((quad * 4 + rg) * 256 + nt * 16 + col) * 8 + h] = f2bf(c[rg]);
            }
        }
        float* rdst = out + 2097152 + rbase;
#pragma unroll
        for (int r = 0; r < 8; ++r)
#pragma unroll
            for (int j = 0; j < 4; ++j) {
                int nm = r * 256 + j * 64 + lane;
                float v = rv[r * 4 + j];
                rdst[nm] = v;                 // fp32 passthrough copy (exact)
                rb[nm * 8 + h] = f2bf(v);     // stage transposed
            }
    }
    __syncthreads();

    float lg[4][16];   // logits: [head rg][t8]
    {   // P2: score_aggr via exact k=16 MFMAs; hidden+logits in registers
        bf16x8 a1 = pad4(*(const bf16x4*)&saw1t16[col][quad4]);
        bf16x8 a2 = pad4(*(const bf16x4*)&saw2t16[col][quad4]);
        f32x4 bv1 = *(const f32x4*)&b1s[quad4];
        const char* aptr = (const char*)((quad & 2) ? rb : sb) + (quad & 1) * 8;
        const int rowbase = (w * 256 + col) * 16;

        bf16x4 b4 = *(const bf16x4*)(aptr + rowbase);
#pragma unroll
        for (int t8 = 0; t8 < 16; ++t8) {
            bf16x8 b1 = pad4(b4);
            if (t8 < 15) b4 = *(const bf16x4*)(aptr + rowbase + (t8 + 1) * 256);
            f32x4 c1 = mfma16(a1, b1, zero);
            unsigned q0 = cvtpk(fmaxf(c1[0] + bv1[0], 0.f), fmaxf(c1[1] + bv1[1], 0.f));
            unsigned q1 = cvtpk(fmaxf(c1[2] + bv1[2], 0.f), fmaxf(c1[3] + bv1[3], 0.f));
            f32x4 c2 = mfma16(a2, u4bf(q0, q1, 0, 0), zero);
#pragma unroll
            for (int rg = 0; rg < 4; ++rg) lg[rg][t8] = c2[rg];
        }
    }

    float inv[4];
    {   // P3: register softmax over m=256 per (head, n=w)
#pragma unroll
        for (int rg = 0; rg < 4; ++rg) {
            float mx = lg[rg][0];
#pragma unroll
            for (int t = 1; t < 16; ++t) mx = fmaxf(mx, lg[rg][t]);
#pragma unroll
            for (int off = 1; off < 16; off <<= 1) mx = fmaxf(mx, __shfl_xor(mx, off, 64));
            float s = 0.f;
#pragma unroll
            for (int t = 0; t < 16; ++t) {
                float e = __expf(lg[rg][t] - mx);
                lg[rg][t] = e; s += e;
            }
#pragma unroll
            for (int off = 1; off < 16; off <<= 1) s += __shfl_xor(s, off, 64);
            inv[rg] = 1.f / s;
        }
    }
    __syncthreads();   // all P2 reads done before soft overwrites sb

    {   // P3b: write soft bf16 into per-head slabs (XOR-swizzled), quads 0,1
        if (quad < 2) {
            const int swz = w << 4;
#pragma unroll
            for (int rg = 0; rg < 4; ++rg) {
                char* slab = (char*)srb + (quad4 + rg) * 4096 + w * 512;
                float iv = inv[rg];
#pragma unroll
                for (int t = 0; t < 16; ++t)
                    *(__hip_bfloat16*)(slab + (((t * 16 + col) * 2) ^ swz)) = f2bf(lg[rg][t] * iv);
            }
        }
    }
    __syncthreads();

    {   // P4: PV (wave w <-> head h=w)
        const int h = w;
        f32x4 acc = zero;
        const __hip_bfloat16* Vh = Vtb + ((size_t)(b * 8 + h)) * 16 * 256;
        const char* softh = (const char*)srb + h * 4096 + (col & 7) * 512;
        const int sx = (col & 7) << 4;
#pragma unroll
        for (int ks = 0; ks < 8; ++ks) {
            bf16x8 a = *(const bf16x8*)(softh + ((ks * 64 + quad * 16) ^ sx));
            bf16x8 bv = ld8(Vh + (size_t)col * 256 + ks * 32 + quad * 8);
            acc = mfma16(a, bv, acc);
        }
        if (quad < 2) {
#pragma unroll
            for (int rg = 0; rg < 4; ++rg)
                headsb[quad * 4 + rg][h * 16 + col] = f2bf(acc[rg]);
        }
    }
    __syncthreads();

    {   // P5: out-proj + residual -> y (fp32) + LN1 stats (block-reduced)
        f32x4 acc = zero;
#pragma unroll
        for (int ks = 0; ks < 4; ++ks) {
            bf16x8 a = *(const bf16x8*)&headsb[col & 7][ks * 32 + quad * 8];
            bf16x8 bo = ld8(Wot + (size_t)(w * 16 + col) * 128 + ks * 32 + quad * 8);
            acc = mfma16(a, bo, acc);
        }
        float s = 0.f, sq = 0.f;
        if (quad < 2) {
#pragma unroll
            for (int rg = 0; rg < 4; ++rg) {
                int n = n0 + quad * 4 + rg, d = w * 16 + col;
                size_t idx = ((size_t)b * 256 + n) * 128 + d;
                float yv_ = acc[rg] + h_em[idx];
                y[idx] = yv_;
                s += yv_; sq += yv_ * yv_;
            }
        }
#pragma unroll
        for (int off = 32; off; off >>= 1) {
            s += __shfl_xor(s, off, 64);
            sq += __shfl_xor(sq, off, 64);
        }
        if (lane == 0) { psum[w] = s; qsum[w] = sq; }
        __syncthreads();
        if (tid == 0) {
            float S = 0.f, Q = 0.f;
#pragma unroll
            for (int i = 0; i < 8; ++i) { S += psum[i]; Q += qsum[i]; }
            atomicAdd(&stats1[b * 32], S);
            atomicAdd(&stats1[b * 32 + 1], Q);
        }
    }
}

// K3: fused LN1-apply + FF + residual + LN2-stats. 32-row tiles, in-place y->y2.
__global__ __launch_bounds__(512) void ffln_kernel(
    float* __restrict__ y, const float* __restrict__ stats1,
    const __hip_bfloat16* __restrict__ w1t, const __hip_bfloat16* __restrict__ w2t,
    float* __restrict__ stats2)
{
    __shared__ alignas(16) __hip_bfloat16 xt[32][136];
    __shared__ alignas(16) __hip_bfloat16 hid[32][520];
    __shared__ float psum[8], qsum[8];
    const int tid = threadIdx.x;
    const int w = tid >> 6, lane = tid & 63;
    const int quad = lane >> 4, col = lane & 15;
    const int r0 = blockIdx.x * 32, b = r0 >> 8;

    float s1 = stats1[b * 32], q1 = stats1[b * 32 + 1];
    float mean = s1 * (1.f / 32768.f);
    float var = fmaxf((q1 - s1 * mean) * (1.f / 32767.f), 0.f);
    float rstd = rsqrtf(var + 1e-5f);

    {   // LN1-apply head: load y tile coalesced, normalize, stage bf16
        int r = tid >> 4, c8 = (tid & 15) * 8;
        const float* p = y + (size_t)(r0 + r) * 128 + c8;
        f32x4 u = *reinterpret_cast<const f32x4*>(p);
        f32x4 v = *reinterpret_cast<const f32x4*>(p + 4);
        bf16x8 xv;
#pragma unroll
        for (int j = 0; j < 4; ++j) xv[j] = (__bf16)((u[j] - mean) * rstd);
#pragma unroll
        for (int j = 0; j < 4; ++j) xv[4 + j] = (__bf16)((v[j] - mean) * rstd);
        *reinterpret_cast<bf16x8*>(&xt[r][c8]) = xv;
    }
    __syncthreads();

    f32x4 acc[2][4] = {};
#pragma unroll
    for (int ks = 0; ks < 4; ++ks) {
        bf16x8 a[2], bb[4];
#pragma unroll
        for (int mt = 0; mt < 2; ++mt)
            a[mt] = ld8(&xt[mt * 16 + col][ks * 32 + quad * 8]);
#pragma unroll
        for (int nt = 0; nt < 4; ++nt) {
            int f = (w * 4 + nt) * 16 + col;
            bb[nt] = ld8(w1t + (size_t)f * 128 + ks * 32 + quad * 8);
        }
#pragma unroll
        for (int mt = 0; mt < 2; ++mt)
#pragma unroll
            for (int nt = 0; nt < 4; ++nt)
                acc[mt][nt] = mfma16(a[mt], bb[nt], acc[mt][nt]);
    }
#pragma unroll
    for (int mt = 0; mt < 2; ++mt)
#pragma unroll
        for (int nt = 0; nt < 4; ++nt)
#pragma unroll
            for (int rg = 0; rg < 4; ++rg) {
                int row = mt * 16 + quad * 4 + rg;
                int f = (w * 4 + nt) * 16 + col;
                hid[row][f] = f2bf(fmaxf(acc[mt][nt][rg], 0.f));
            }
    __syncthreads();

    f32x4 acc2[2] = {};
#pragma unroll
    for (int ks = 0; ks < 16; ++ks) {
        bf16x8 bb = ld8(w2t + (size_t)(w * 16 + col) * 512 + ks * 32 + quad * 8);
#pragma unroll
        for (int mt = 0; mt < 2; ++mt) {
            bf16x8 a = *(const bf16x8*)&hid[mt * 16 + col][ks * 32 + quad * 8];
            acc2[mt] = mfma16(a, bb, acc2[mt]);
        }
    }
    float s = 0.f, sq = 0.f;
#pragma unroll
    for (int mt = 0; mt < 2; ++mt)
#pragma unroll
        for (int rg = 0; rg < 4; ++rg) {
            int row = r0 + mt * 16 + quad * 4 + rg;
            int d = w * 16 + col;
            size_t idx = (size_t)row * 128 + d;
            float xn = (y[idx] - mean) * rstd;   // fp32 residual (L2-hot re-read)
            float o = acc2[mt][rg] + xn;
            y[idx] = o;                          // in-place: own idx only
            s += o; sq += o * o;
        }
#pragma unroll
    for (int off = 32; off; off >>= 1) {
        s += __shfl_xor(s, off, 64);
        sq += __shfl_xor(sq, off, 64);
    }
    if (lane == 0) { psum[w] = s; qsum[w] = sq; }
    __syncthreads();
    if (tid == 0) {
        float S = 0.f, Q = 0.f;
#pragma unroll
        for (int i = 0; i < 8; ++i) { S += psum[i]; Q += qsum[i]; }
        atomicAdd(&stats2[b * 32], S);
        atomicAdd(&stats2[b * 32 + 1], Q);
    }
}

// K4: LN2 apply, wide grid. 2048 blocks x 256 thr x float4 = 2,097,152 elems.
__global__ __launch_bounds__(256) void ln_apply_kernel(
    const float* __restrict__ y2, const float* __restrict__ stats2,
    float* __restrict__ out1)
{
    int i = (blockIdx.x * 256 + threadIdx.x) * 4;
    int b = i >> 15;
    float s = stats2[b * 32], q = stats2[b * 32 + 1];
    float mean = s * (1.f / 32768.f);
    float var = fmaxf((q - s * mean) * (1.f / 32767.f), 0.f);
    float rstd = rsqrtf(var + 1e-5f);
    f32x4 v = *reinterpret_cast<const f32x4*>(&y2[i]);
#pragma unroll
    for (int j = 0; j < 4; ++j) v[j] = (v[j] - mean) * rstd;
    *reinterpret_cast<f32x4*>(&out1[i]) = v;
}

extern "C" void kernel_launch(void* const* d_in, const int* in_sizes, int n_in,
                              void* d_out, int out_size, void* d_ws, size_t ws_size,
                              hipStream_t stream)
{
    const float* h_em  = (const float*)d_in[0];
    const float* route = (const float*)d_in[1];
    const float* Wq    = (const float*)d_in[2];
    const float* Wk    = (const float*)d_in[3];
    const float* Wv    = (const float*)d_in[4];
    const float* W_out = (const float*)d_in[5];
    const float* sa_w1 = (const float*)d_in[6];
    const float* sa_b1 = (const float*)d_in[7];
    const float* sa_w2 = (const float*)d_in[8];
    const float* sa_b2 = (const float*)d_in[9];
    const float* ff_w1 = (const float*)d_in[10];
    const float* ff_w2 = (const float*)d_in[11];

    char* ws = (char*)d_ws;
    __hip_bfloat16* Qb    = (__hip_bfloat16*)(ws);
    __hip_bfloat16* Kb    = (__hip_bfloat16*)(ws + 4194304);
    __hip_bfloat16* Vtb   = (__hip_bfloat16*)(ws + 8388608);
    __hip_bfloat16* Wqkvt = (__hip_bfloat16*)(ws + 12582912);
    __hip_bfloat16* Wot   = (__hip_bfloat16*)(ws + 12681216);
    __hip_bfloat16* w1t   = (__hip_bfloat16*)(ws + 12713984);
    __hip_bfloat16* w2t   = (__hip_bfloat16*)(ws + 12845056);
    float*          yv    = (float*)(ws + 12976128);
    float*          stats = (float*)(ws + 21364736);  // stats1[2048] | stats2[2048]
    float*          stats1 = stats;
    float*          stats2 = stats + 2048;

    hipLaunchKernelGGL(repack_kernel, dim3(768), dim3(256), 0, stream,
                       Wq, Wk, Wv, W_out, ff_w1, ff_w2, Wqkvt, Wot, w1t, w2t, stats);
    hipLaunchKernelGGL(qkv_kernel, dim3(512), dim3(512), 0, stream,
                       h_em, Wqkvt, Qb, Kb, Vtb);
    hipLaunchKernelGGL(attn_kernel_v7, dim3(2048), dim3(512), 0, stream,
                       Qb, Kb, Vtb, route, sa_w1, sa_b1, sa_w2, sa_b2, h_em, Wot,
                       yv, (float*)d_out, stats1);
    hipLaunchKernelGGL(ffln_kernel, dim3(512), dim3(512), 0, stream,
                       yv, stats1, w1t, w2t, stats2);
    hipLaunchKernelGGL(ln_apply_kernel, dim3(2048), dim3(256), 0, stream,
                       yv, stats2, (float*)d_out);
}